// Round 1
// baseline (764.762 us; speedup 1.0000x reference)
//
#include <hip/hip_runtime.h>
#include <stdint.h>

#define NJ 316  // L*P + Lx = 16 + 300

// ---------------------------------------------------------------------------
// Kernel 1: off = query @ W_off^T + b_off (fp64 accum), then sampling indices
// lin[q][h*16+l*4+p]. fp64 so the (int) truncation matches an fp64 reference.
// ---------------------------------------------------------------------------
__global__ __launch_bounds__(256) void lin_kernel(
    const float* __restrict__ query, const float* __restrict__ refp,
    const int* __restrict__ iss, const int* __restrict__ lsi,
    const float* __restrict__ Woff, const float* __restrict__ boff,
    int* __restrict__ lin)
{
    __shared__ float qf8[8][256];
    __shared__ float wtile[256][33];   // +1 pad: conflict-free strided reads
    __shared__ double offl[8][256];
    const int t = threadIdx.x;
    const int qbase = blockIdx.x * 8;
    #pragma unroll
    for (int i = 0; i < 8; ++i) qf8[i][t] = query[(qbase + i) * 256 + t];
    double acc[8];
    #pragma unroll
    for (int r = 0; r < 8; ++r) acc[r] = 0.0;
    for (int cb = 0; cb < 256; cb += 32) {
        __syncthreads();
        #pragma unroll
        for (int i = 0; i < 32; ++i) {
            int f = i * 256 + t;
            int o = f >> 5, jj = f & 31;
            wtile[o][jj] = Woff[o * 256 + cb + jj];
        }
        __syncthreads();
        #pragma unroll
        for (int jj = 0; jj < 32; ++jj) {
            double wv = (double)wtile[t][jj];
            #pragma unroll
            for (int r = 0; r < 8; ++r)
                acc[r] += (double)qf8[r][cb + jj] * wv;
        }
    }
    double bo = (double)boff[t];
    __syncthreads();
    #pragma unroll
    for (int r = 0; r < 8; ++r) offl[r][t] = acc[r] + bo;
    __syncthreads();
    #pragma unroll
    for (int rep = 0; rep < 4; ++rep) {
        int idx = rep * 256 + t;          // 8 q-rows * 128 samples
        int r = idx >> 7;
        int s = idx & 127;                // h*16 + l*4 + p
        int l = (s >> 2) & 3;
        int q = qbase + r;
        double offx = offl[r][2 * s];
        double offy = offl[r][2 * s + 1];
        int w0 = iss[l * 2 + 0];
        int w1 = iss[l * 2 + 1];
        // loc = ref + off / iss[:, ::-1]
        double locx = (double)refp[q * 8 + l * 2 + 0] + offx / (double)w1;
        double locy = (double)refp[q * 8 + l * 2 + 1] + offy / (double)w0;
        locx = fmin(fmax(locx, 0.0), 0.999);
        locy = fmin(fmax(locy, 0.0), 0.999);
        int ix = (int)(locx * (double)w0);
        int iy = (int)(locy * (double)w1);
        lin[q * 128 + s] = ix + iy * w0 + lsi[l];
    }
}

// ---------------------------------------------------------------------------
// Kernel 2: fused G + scrambled attn_s.
// Per block (h,l,p,qb): G[hi,e] = sum_j qf[q2(hi),j] * key(256*qb+j)[e]
//   with q2(hi) = qb + 8p + 32hi  (64x256 tile, K=256 over j)
// then attn_s[h,l,p2,q2] = sum_e Ws[h,l, hi+64*p2, e] * G[hi,e].
// 1024 blocks = exactly 4 per CU.
// ---------------------------------------------------------------------------
__global__ __launch_bounds__(256) void gattn_kernel(
    const float* __restrict__ query, const float* __restrict__ inflat,
    const float* __restrict__ Wattn, const int* __restrict__ lin,
    float* __restrict__ attn)
{
    __shared__ float Klds[16 * 256];
    __shared__ float Qlds[16 * 68];    // stride 68: 16B-aligned, conflict-free
    __shared__ int linrow[256];
    const int t = threadIdx.x;
    const int b = blockIdx.x;
    const int qb = b & 7, p = (b >> 3) & 3, l = (b >> 5) & 3, h = b >> 7;
    linrow[t] = lin[(256 * qb + t) * 128 + h * 16 + l * 4 + p];
    const int tx = t & 15, ty = t >> 4;
    const int q2base = qb + 8 * p;
    float acc[4][16];                   // 4 hi x 16 e per thread
    #pragma unroll
    for (int r = 0; r < 4; ++r)
        #pragma unroll
        for (int i = 0; i < 16; ++i) acc[r][i] = 0.f;

    for (int jb = 0; jb < 256; jb += 16) {
        __syncthreads();
        #pragma unroll
        for (int i = 0; i < 16; ++i) {
            int row = linrow[jb + i];
            Klds[i * 256 + t] = inflat[row * 256 + t];
        }
        #pragma unroll
        for (int i = 0; i < 4; ++i) {
            int f = i * 256 + t;
            int hi = f >> 4, jj = f & 15;
            Qlds[jj * 68 + hi] = query[(q2base + 32 * hi) * 256 + jb + jj];
        }
        __syncthreads();
        #pragma unroll
        for (int jj = 0; jj < 16; ++jj) {
            float4 qv4 = *(const float4*)&Qlds[jj * 68 + ty * 4];
            float qv[4] = {qv4.x, qv4.y, qv4.z, qv4.w};
            #pragma unroll
            for (int i2 = 0; i2 < 4; ++i2) {
                float4 kv = *(const float4*)&Klds[jj * 256 + tx * 4 + 64 * i2];
                #pragma unroll
                for (int r = 0; r < 4; ++r) {
                    acc[r][i2 * 4 + 0] += qv[r] * kv.x;
                    acc[r][i2 * 4 + 1] += qv[r] * kv.y;
                    acc[r][i2 * 4 + 2] += qv[r] * kv.z;
                    acc[r][i2 * 4 + 3] += qv[r] * kv.w;
                }
            }
        }
    }
    // epilogue: contract G rows with Ws rows, reduce over the 16 tx lanes
    const float* Wsbase = Wattn + (size_t)(h * 4 + l) * 65536;
    #pragma unroll
    for (int r = 0; r < 4; ++r) {
        int hi = ty * 4 + r;
        int q2 = q2base + 32 * hi;
        #pragma unroll
        for (int p2 = 0; p2 < 4; ++p2) {
            const float* wr = Wsbase + (size_t)(hi + 64 * p2) * 256;
            float partial = 0.f;
            #pragma unroll
            for (int i2 = 0; i2 < 4; ++i2) {
                float4 wv = *(const float4*)&wr[tx * 4 + 64 * i2];
                partial += wv.x * acc[r][i2 * 4 + 0] + wv.y * acc[r][i2 * 4 + 1]
                         + wv.z * acc[r][i2 * 4 + 2] + wv.w * acc[r][i2 * 4 + 3];
            }
            partial += __shfl_xor(partial, 1);
            partial += __shfl_xor(partial, 2);
            partial += __shfl_xor(partial, 4);
            partial += __shfl_xor(partial, 8);
            if (tx == 0)
                attn[((size_t)h * 2048 + q2) * NJ + (l * 4 + p2)] = partial;
        }
    }
}

// ---------------------------------------------------------------------------
// Generic batched fp32 GEMM: C[z] (+)= A[z](MxK) * B[z]^T-ish.
// B_KN=false: B is N rows x K cols (NT).  B_KN=true: B is K rows x N cols (NN).
// 128x128 tile, BK=32, 8x8 acc per thread.
// ---------------------------------------------------------------------------
template<bool B_KN, bool ACCUM>
__global__ __launch_bounds__(256) void gemm_kernel(
    const float* __restrict__ A, const float* __restrict__ B, float* __restrict__ Cc,
    int M, int N, int K, int lda, int ldb, int ldc,
    long sA, long sB, long sC)
{
    __shared__ float As[32][132];  // [k][m], +4 pad keeps b128 reads aligned
    __shared__ float Bs[32][132];  // [k][n]
    const int t = threadIdx.x;
    const int tx = t & 15, ty = t >> 4;
    const int nb = blockIdx.x * 128, mb = blockIdx.y * 128;
    const int z = blockIdx.z;
    const float* Az = A + (size_t)z * sA;
    const float* Bz = B + (size_t)z * sB;
    float* Cz = Cc + (size_t)z * sC;
    float acc[2][2][4][4];
    #pragma unroll
    for (int a = 0; a < 2; ++a)
        #pragma unroll
        for (int bq = 0; bq < 2; ++bq)
            #pragma unroll
            for (int r = 0; r < 4; ++r)
                #pragma unroll
                for (int j = 0; j < 4; ++j) acc[a][bq][r][j] = 0.f;

    for (int kb = 0; kb < K; kb += 32) {
        __syncthreads();
        #pragma unroll
        for (int i = 0; i < 16; ++i) {
            int f = i * 256 + t;
            int m = f >> 5, jj = f & 31;
            int gm = mb + m, gk = kb + jj;
            As[jj][m] = (gm < M && gk < K) ? Az[(size_t)gm * lda + gk] : 0.f;
        }
        #pragma unroll
        for (int i = 0; i < 16; ++i) {
            int f = i * 256 + t;
            if (B_KN) {
                int n = f & 127, jj = f >> 7;
                int gn = nb + n, gk = kb + jj;
                Bs[jj][n] = (gn < N && gk < K) ? Bz[(size_t)gk * ldb + gn] : 0.f;
            } else {
                int n = f >> 5, jj = f & 31;
                int gn = nb + n, gk = kb + jj;
                Bs[jj][n] = (gn < N && gk < K) ? Bz[(size_t)gn * ldb + gk] : 0.f;
            }
        }
        __syncthreads();
        #pragma unroll
        for (int jj = 0; jj < 32; ++jj) {
            float4 a0 = *(const float4*)&As[jj][ty * 4];
            float4 a1 = *(const float4*)&As[jj][ty * 4 + 64];
            float4 b0 = *(const float4*)&Bs[jj][tx * 4];
            float4 b1 = *(const float4*)&Bs[jj][tx * 4 + 64];
            float aa[2][4] = {{a0.x, a0.y, a0.z, a0.w}, {a1.x, a1.y, a1.z, a1.w}};
            float bb[2][4] = {{b0.x, b0.y, b0.z, b0.w}, {b1.x, b1.y, b1.z, b1.w}};
            #pragma unroll
            for (int im = 0; im < 2; ++im)
                #pragma unroll
                for (int r = 0; r < 4; ++r)
                    #pragma unroll
                    for (int in = 0; in < 2; ++in)
                        #pragma unroll
                        for (int j = 0; j < 4; ++j)
                            acc[im][in][r][j] += aa[im][r] * bb[in][j];
        }
    }
    #pragma unroll
    for (int im = 0; im < 2; ++im)
        #pragma unroll
        for (int r = 0; r < 4; ++r) {
            int gm = mb + ty * 4 + r + 64 * im;
            if (gm >= M) continue;
            #pragma unroll
            for (int in = 0; in < 2; ++in)
                #pragma unroll
                for (int j = 0; j < 4; ++j) {
                    int gn = nb + tx * 4 + j + 64 * in;
                    if (gn >= N) continue;
                    size_t idx = (size_t)gm * ldc + gn;
                    float prev = ACCUM ? Cz[idx] : 0.f;
                    Cz[idx] = prev + acc[im][in][r][j];
                }
        }
}

// ---------------------------------------------------------------------------
// Kernel: softmax over the 316 concatenated logits per (h,q); also s0 = sum of
// the first 16 (sampled) weights, used for the bv0/bv1 bias split.
// ---------------------------------------------------------------------------
__global__ __launch_bounds__(256) void softmax_kernel(
    float* __restrict__ attn, float* __restrict__ s0)
{
    const int t = threadIdx.x;
    const int w = t >> 6, lane = t & 63;
    const int rid = blockIdx.x * 4 + w;     // h*2048 + q
    float* row = attn + (size_t)rid * NJ;
    float v[5];
    float m = -1e30f;
    #pragma unroll
    for (int i = 0; i < 5; ++i) {
        int j = lane + 64 * i;
        v[i] = (j < NJ) ? row[j] : -1e30f;
        m = fmaxf(m, v[i]);
    }
    #pragma unroll
    for (int d = 1; d < 64; d <<= 1) m = fmaxf(m, __shfl_xor(m, d));
    float s = 0.f, sfirst = 0.f;
    #pragma unroll
    for (int i = 0; i < 5; ++i) {
        int j = lane + 64 * i;
        float e = (j < NJ) ? expf(v[i] - m) : 0.f;
        v[i] = e;
        s += e;
        if (i == 0 && lane < 16) sfirst += e;
    }
    #pragma unroll
    for (int d = 1; d < 64; d <<= 1) s += __shfl_xor(s, d);
    #pragma unroll
    for (int d = 1; d < 64; d <<= 1) sfirst += __shfl_xor(sfirst, d);
    float inv = 1.f / s;
    #pragma unroll
    for (int i = 0; i < 5; ++i) {
        int j = lane + 64 * i;
        if (j < NJ) row[j] = v[i] * inv;
    }
    if (lane == 0) s0[rid] = sfirst * inv;
}

// ---------------------------------------------------------------------------
// Kernel: KA[h,q,e] = sum_{k<16} attn[h,q,k] * key_row(lin[q,h,k])[e]
// (attention weighting hoisted before the value projection)
// ---------------------------------------------------------------------------
__global__ __launch_bounds__(256) void ka_kernel(
    const float* __restrict__ inflat, const float* __restrict__ attn,
    const int* __restrict__ lin, float* __restrict__ KA)
{
    __shared__ float wls[16];
    __shared__ int lls[16];
    const int b = blockIdx.x;               // h*2048 + q
    const int h = b >> 11, q = b & 2047;
    const int t = threadIdx.x;
    if (t < 16) {
        wls[t] = attn[(size_t)b * NJ + t];
        lls[t] = lin[q * 128 + h * 16 + t];
    }
    __syncthreads();
    float acc = 0.f;
    #pragma unroll
    for (int k = 0; k < 16; ++k)
        acc += wls[k] * inflat[lls[k] * 256 + t];
    KA[(size_t)b * 256 + t] = acc;
}

// ---------------------------------------------------------------------------
// Kernel: per-channel head softmax + final mix with bias terms.
// ---------------------------------------------------------------------------
__global__ __launch_bounds__(256) void final_kernel(
    const float* __restrict__ qf, const float* __restrict__ OH,
    const float* __restrict__ s0, const float* __restrict__ bv,
    const float* __restrict__ Wmix, float* __restrict__ out)
{
    const int q = blockIdx.x, c = threadIdx.x;
    float wj[9], m = -1e30f;
    #pragma unroll
    for (int j = 0; j < 9; ++j) { wj[j] = Wmix[c * 9 + j]; m = fmaxf(m, wj[j]); }
    float s = 0.f;
    #pragma unroll
    for (int j = 0; j < 9; ++j) { wj[j] = expf(wj[j] - m); s += wj[j]; }
    float inv = 1.f / s;
    float acc = qf[q * 256 + c] * wj[8] * inv;
    #pragma unroll
    for (int h = 0; h < 8; ++h) {
        float s0v = s0[h * 2048 + q];
        float oh = OH[((size_t)h * 2048 + q) * 256 + c]
                 + s0v * bv[(2 * h) * 256 + c]
                 + (1.f - s0v) * bv[(2 * h + 1) * 256 + c];
        acc += oh * wj[h] * inv;
    }
    out[q * 256 + c] = acc;
}

// ---------------------------------------------------------------------------
extern "C" void kernel_launch(void* const* d_in, const int* in_sizes, int n_in,
                              void* d_out, int out_size, void* d_ws, size_t ws_size,
                              hipStream_t stream) {
    const float* query = (const float*)d_in[0];
    const float* refp  = (const float*)d_in[1];
    const float* inflat= (const float*)d_in[2];
    const int*   iss   = (const int*)d_in[3];
    const float* ak    = (const float*)d_in[4];
    const int*   lsi   = (const int*)d_in[5];
    const float* Woff  = (const float*)d_in[6];
    const float* boff  = (const float*)d_in[7];
    const float* Wattn = (const float*)d_in[8];
    const float* Wv    = (const float*)d_in[9];
    const float* bv    = (const float*)d_in[10];
    const float* Wmix  = (const float*)d_in[11];
    float* out = (float*)d_out;

    char* ws = (char*)d_ws;
    int* lin    = (int*)ws;    ws += (size_t)262144 * 4;            // [Lq][128]
    float* attn = (float*)ws;  ws += (size_t)8 * 2048 * NJ * 4;     // [H][Lq][316]
    float* Bws  = (float*)ws;  ws += (size_t)8 * 300 * 256 * 4;     // [H][300][256]
    float* s0   = (float*)ws;  ws += (size_t)8 * 2048 * 4;          // [H][Lq]
    float* KA   = (float*)ws;  ws += (size_t)8 * 2048 * 256 * 4;    // [H][Lq][C]
    float* AA   = (float*)ws;  ws += (size_t)8 * 2048 * 256 * 4;
    float* OH   = (float*)ws;  ws += (size_t)8 * 2048 * 256 * 4;
    // total ~75 MB

    lin_kernel<<<256, 256, 0, stream>>>(query, refp, iss, lsi, Woff, boff, lin);

    // Bh = ak @ Wadd[h]^T,  Wadd[h] = W_attn[4h+4]
    gemm_kernel<false, false><<<dim3(2, 3, 8), 256, 0, stream>>>(
        ak, Wattn + 4 * 65536, Bws, 300, 256, 256, 256, 256, 256,
        0L, 4L * 65536, 300L * 256);

    // attn_a logits: qf @ Bh^T -> attn[h][q][16+x]
    gemm_kernel<false, false><<<dim3(3, 16, 8), 256, 0, stream>>>(
        query, Bws, attn + 16, 2048, 300, 256, 256, 256, NJ,
        0L, 300L * 256, 2048L * NJ);

    // fused G + scrambled attn_s -> attn[h][q][0..15]
    gattn_kernel<<<1024, 256, 0, stream>>>(query, inflat, Wattn, lin, attn);

    softmax_kernel<<<4096, 256, 0, stream>>>(attn, s0);

    ka_kernel<<<16384, 256, 0, stream>>>(inflat, attn, lin, KA);

    // AA[h] = attn_a_sm[h] @ ak   (A: lda=316 offset 16, K=300; B in KN layout)
    gemm_kernel<true, false><<<dim3(2, 16, 8), 256, 0, stream>>>(
        attn + 16, ak, AA, 2048, 256, 300, NJ, 256, 256,
        2048L * NJ, 0L, 2048L * 256);

    // OH = KA @ Wv0^T ; OH += AA @ Wv1^T
    gemm_kernel<false, false><<<dim3(2, 16, 8), 256, 0, stream>>>(
        KA, Wv, OH, 2048, 256, 256, 256, 256, 256,
        2048L * 256, 2L * 65536, 2048L * 256);
    gemm_kernel<false, true><<<dim3(2, 16, 8), 256, 0, stream>>>(
        AA, Wv + 65536, OH, 2048, 256, 256, 256, 256, 256,
        2048L * 256, 2L * 65536, 2048L * 256);

    final_kernel<<<2048, 256, 0, stream>>>(query, OH, s0, bv, Wmix, out);
}

// Round 2
// 353.062 us; speedup vs baseline: 2.1661x; 2.1661x over previous
//
#include <hip/hip_runtime.h>
#include <stdint.h>

#define NJ 316  // L*P + Lx = 16 + 300

typedef __attribute__((ext_vector_type(8))) short short8;
typedef __attribute__((ext_vector_type(4))) float f32x4;

__device__ __forceinline__ unsigned short f2bf(float x) {
    unsigned int u = __float_as_uint(x);
    u += 0x7fff + ((u >> 16) & 1);
    return (unsigned short)(u >> 16);
}
__device__ __forceinline__ float bf2f(unsigned short h) {
    return __uint_as_float(((unsigned int)h) << 16);
}

// ---------------------------------------------------------------------------
// Elementwise fp32 -> (hi, lo) bf16 planes. n must be a multiple of 4.
// ---------------------------------------------------------------------------
__global__ __launch_bounds__(256) void cvt_kernel(
    const float* __restrict__ src, unsigned short* __restrict__ dh,
    unsigned short* __restrict__ dl, int n4)
{
    for (int i = blockIdx.x * 256 + threadIdx.x; i < n4; i += gridDim.x * 256) {
        float4 v = ((const float4*)src)[i];
        unsigned short h[4], l[4];
        float x[4] = {v.x, v.y, v.z, v.w};
        #pragma unroll
        for (int j = 0; j < 4; ++j) {
            h[j] = f2bf(x[j]);
            l[j] = f2bf(x[j] - bf2f(h[j]));
        }
        uint2 hp = make_uint2((unsigned)h[0] | ((unsigned)h[1] << 16),
                              (unsigned)h[2] | ((unsigned)h[3] << 16));
        uint2 lp = make_uint2((unsigned)l[0] | ((unsigned)l[1] << 16),
                              (unsigned)l[2] | ((unsigned)l[3] << 16));
        ((uint2*)dh)[i] = hp;
        ((uint2*)dl)[i] = lp;
    }
}

// akT_pad[e][k]: k<16 -> 0, 16<=k<316 -> ak[k-16][e], k>=316 -> 0.  [256][320]
__global__ __launch_bounds__(256) void cvt_akT_kernel(
    const float* __restrict__ ak, unsigned short* __restrict__ dh,
    unsigned short* __restrict__ dl)
{
    const int e = blockIdx.x;
    for (int k = threadIdx.x; k < 320; k += 256) {
        float v = (k >= 16 && k < 316) ? ak[(k - 16) * 256 + e] : 0.f;
        unsigned short h = f2bf(v);
        dh[e * 320 + k] = h;
        dl[e * 320 + k] = f2bf(v - bf2f(h));
    }
}

// ---------------------------------------------------------------------------
// lin_kernel: fp64 offsets -> sampling indices (unchanged, verified R1)
// ---------------------------------------------------------------------------
__global__ __launch_bounds__(256) void lin_kernel(
    const float* __restrict__ query, const float* __restrict__ refp,
    const int* __restrict__ iss, const int* __restrict__ lsi,
    const float* __restrict__ Woff, const float* __restrict__ boff,
    int* __restrict__ lin)
{
    __shared__ float qf8[8][256];
    __shared__ float wtile[256][33];
    __shared__ double offl[8][256];
    const int t = threadIdx.x;
    const int qbase = blockIdx.x * 8;
    #pragma unroll
    for (int i = 0; i < 8; ++i) qf8[i][t] = query[(qbase + i) * 256 + t];
    double acc[8];
    #pragma unroll
    for (int r = 0; r < 8; ++r) acc[r] = 0.0;
    for (int cb = 0; cb < 256; cb += 32) {
        __syncthreads();
        #pragma unroll
        for (int i = 0; i < 32; ++i) {
            int f = i * 256 + t;
            int o = f >> 5, jj = f & 31;
            wtile[o][jj] = Woff[o * 256 + cb + jj];
        }
        __syncthreads();
        #pragma unroll
        for (int jj = 0; jj < 32; ++jj) {
            double wv = (double)wtile[t][jj];
            #pragma unroll
            for (int r = 0; r < 8; ++r)
                acc[r] += (double)qf8[r][cb + jj] * wv;
        }
    }
    double bo = (double)boff[t];
    __syncthreads();
    #pragma unroll
    for (int r = 0; r < 8; ++r) offl[r][t] = acc[r] + bo;
    __syncthreads();
    #pragma unroll
    for (int rep = 0; rep < 4; ++rep) {
        int idx = rep * 256 + t;
        int r = idx >> 7;
        int s = idx & 127;
        int l = (s >> 2) & 3;
        int q = qbase + r;
        double offx = offl[r][2 * s];
        double offy = offl[r][2 * s + 1];
        int w0 = iss[l * 2 + 0];
        int w1 = iss[l * 2 + 1];
        double locx = (double)refp[q * 8 + l * 2 + 0] + offx / (double)w1;
        double locy = (double)refp[q * 8 + l * 2 + 1] + offy / (double)w0;
        locx = fmin(fmax(locx, 0.0), 0.999);
        locy = fmin(fmax(locy, 0.0), 0.999);
        int ix = (int)(locx * (double)w0);
        int iy = (int)(locy * (double)w1);
        lin[q * 128 + s] = ix + iy * w0 + lsi[l];
    }
}

// ---------------------------------------------------------------------------
// gattn: fused G + scrambled attn_s (fp32, unchanged from R1 — next target)
// ---------------------------------------------------------------------------
__global__ __launch_bounds__(256) void gattn_kernel(
    const float* __restrict__ query, const float* __restrict__ inflat,
    const float* __restrict__ Wattn, const int* __restrict__ lin,
    float* __restrict__ attn)
{
    __shared__ float Klds[16 * 256];
    __shared__ float Qlds[16 * 68];
    __shared__ int linrow[256];
    const int t = threadIdx.x;
    const int b = blockIdx.x;
    const int qb = b & 7, p = (b >> 3) & 3, l = (b >> 5) & 3, h = b >> 7;
    linrow[t] = lin[(256 * qb + t) * 128 + h * 16 + l * 4 + p];
    const int tx = t & 15, ty = t >> 4;
    const int q2base = qb + 8 * p;
    float acc[4][16];
    #pragma unroll
    for (int r = 0; r < 4; ++r)
        #pragma unroll
        for (int i = 0; i < 16; ++i) acc[r][i] = 0.f;

    for (int jb = 0; jb < 256; jb += 16) {
        __syncthreads();
        #pragma unroll
        for (int i = 0; i < 16; ++i) {
            int row = linrow[jb + i];
            Klds[i * 256 + t] = inflat[row * 256 + t];
        }
        #pragma unroll
        for (int i = 0; i < 4; ++i) {
            int f = i * 256 + t;
            int hi = f >> 4, jj = f & 15;
            Qlds[jj * 68 + hi] = query[(q2base + 32 * hi) * 256 + jb + jj];
        }
        __syncthreads();
        #pragma unroll
        for (int jj = 0; jj < 16; ++jj) {
            float4 qv4 = *(const float4*)&Qlds[jj * 68 + ty * 4];
            float qv[4] = {qv4.x, qv4.y, qv4.z, qv4.w};
            #pragma unroll
            for (int i2 = 0; i2 < 4; ++i2) {
                float4 kv = *(const float4*)&Klds[jj * 256 + tx * 4 + 64 * i2];
                #pragma unroll
                for (int r = 0; r < 4; ++r) {
                    acc[r][i2 * 4 + 0] += qv[r] * kv.x;
                    acc[r][i2 * 4 + 1] += qv[r] * kv.y;
                    acc[r][i2 * 4 + 2] += qv[r] * kv.z;
                    acc[r][i2 * 4 + 3] += qv[r] * kv.w;
                }
            }
        }
    }
    const float* Wsbase = Wattn + (size_t)(h * 4 + l) * 65536;
    #pragma unroll
    for (int r = 0; r < 4; ++r) {
        int hi = ty * 4 + r;
        int q2 = q2base + 32 * hi;
        #pragma unroll
        for (int p2 = 0; p2 < 4; ++p2) {
            const float* wr = Wsbase + (size_t)(hi + 64 * p2) * 256;
            float partial = 0.f;
            #pragma unroll
            for (int i2 = 0; i2 < 4; ++i2) {
                float4 wv = *(const float4*)&wr[tx * 4 + 64 * i2];
                partial += wv.x * acc[r][i2 * 4 + 0] + wv.y * acc[r][i2 * 4 + 1]
                         + wv.z * acc[r][i2 * 4 + 2] + wv.w * acc[r][i2 * 4 + 3];
            }
            partial += __shfl_xor(partial, 1);
            partial += __shfl_xor(partial, 2);
            partial += __shfl_xor(partial, 4);
            partial += __shfl_xor(partial, 8);
            if (tx == 0)
                attn[((size_t)h * 2048 + q2) * NJ + (l * 4 + p2)] = partial;
        }
    }
}

// ---------------------------------------------------------------------------
// Split-bf16 MFMA GEMM.  C[m][n] (+)= sum_seg sum_k A[m][k]*B[n][k] with
// A ~ Ah+Al, B ~ Bh+Bl (3-product split, fp32 accum).  BM=64 BN=128 BK=32,
// 4 waves, wave-tile 32x64 via 16x16x32 bf16 MFMA.
// OUTF32: write fp32 C (ACCUM optionally RMW). else: write hi/lo bf16 planes.
// ---------------------------------------------------------------------------
struct Seg {
    const unsigned short *Ah, *Al, *Bh, *Bl;
    int K, lda, ldb;
    long sA, sB;
};

template<bool ACCUM, bool OUTF32, int NSEG>
__global__ __launch_bounds__(256) void mfma_gemm(
    Seg s0, Seg s1,
    float* __restrict__ Cf, unsigned short* __restrict__ Ch,
    unsigned short* __restrict__ Cl,
    int M, int N, int ldc, long sC)
{
    __shared__ unsigned short As[2][64 * 40];   // [plane][row*40 + k], +8 pad
    __shared__ unsigned short Bs[2][128 * 40];
    const int t = threadIdx.x;
    const int lane = t & 63;
    const int wave = t >> 6;
    const int wm = (wave & 1) * 32, wn = (wave >> 1) * 64;
    const int nb = blockIdx.x * 128, mb = blockIdx.y * 64;
    const int z = blockIdx.z;

    f32x4 acc[2][4];
    #pragma unroll
    for (int i = 0; i < 2; ++i)
        #pragma unroll
        for (int j = 0; j < 4; ++j) acc[i][j] = (f32x4){0.f, 0.f, 0.f, 0.f};

    const int arow = t >> 2, akoff = (t & 3) * 8;      // A: 1 load/plane
    const int frow = lane & 15, fk = (lane >> 4) * 8;  // fragment addressing

    #pragma unroll
    for (int seg = 0; seg < NSEG; ++seg) {
        const Seg S = seg ? s1 : s0;
        const unsigned short* Azh = S.Ah + (size_t)z * S.sA;
        const unsigned short* Azl = S.Al + (size_t)z * S.sA;
        const unsigned short* Bzh = S.Bh + (size_t)z * S.sB;
        const unsigned short* Bzl = S.Bl + (size_t)z * S.sB;
        for (int kb = 0; kb < S.K; kb += 32) {
            __syncthreads();
            {
                int gm = mb + arow;
                uint4 vh = {0, 0, 0, 0}, vl = {0, 0, 0, 0};
                if (gm < M) {
                    size_t o = (size_t)gm * S.lda + kb + akoff;
                    vh = *(const uint4*)(Azh + o);
                    vl = *(const uint4*)(Azl + o);
                }
                *(uint4*)&As[0][arow * 40 + akoff] = vh;
                *(uint4*)&As[1][arow * 40 + akoff] = vl;
                #pragma unroll
                for (int i = 0; i < 2; ++i) {
                    int f = i * 256 + t;
                    int brow = f >> 2, bkoff = (f & 3) * 8;
                    int gn = nb + brow;
                    uint4 wh = {0, 0, 0, 0}, wl = {0, 0, 0, 0};
                    if (gn < N) {
                        size_t o = (size_t)gn * S.ldb + kb + bkoff;
                        wh = *(const uint4*)(Bzh + o);
                        wl = *(const uint4*)(Bzl + o);
                    }
                    *(uint4*)&Bs[0][brow * 40 + bkoff] = wh;
                    *(uint4*)&Bs[1][brow * 40 + bkoff] = wl;
                }
            }
            __syncthreads();
            short8 a[2][2], b[4][2];
            #pragma unroll
            for (int i = 0; i < 2; ++i) {
                int r = wm + i * 16 + frow;
                a[i][0] = *(const short8*)&As[0][r * 40 + fk];
                a[i][1] = *(const short8*)&As[1][r * 40 + fk];
            }
            #pragma unroll
            for (int j = 0; j < 4; ++j) {
                int r = wn + j * 16 + frow;
                b[j][0] = *(const short8*)&Bs[0][r * 40 + fk];
                b[j][1] = *(const short8*)&Bs[1][r * 40 + fk];
            }
            #pragma unroll
            for (int i = 0; i < 2; ++i)
                #pragma unroll
                for (int j = 0; j < 4; ++j) {
                    acc[i][j] = __builtin_amdgcn_mfma_f32_16x16x32_bf16(
                        a[i][0], b[j][0], acc[i][j], 0, 0, 0);
                    acc[i][j] = __builtin_amdgcn_mfma_f32_16x16x32_bf16(
                        a[i][0], b[j][1], acc[i][j], 0, 0, 0);
                    acc[i][j] = __builtin_amdgcn_mfma_f32_16x16x32_bf16(
                        a[i][1], b[j][0], acc[i][j], 0, 0, 0);
                }
        }
    }
    // epilogue: C/D layout col=lane&15, row=(lane>>4)*4+reg
    #pragma unroll
    for (int i = 0; i < 2; ++i)
        #pragma unroll
        for (int r = 0; r < 4; ++r) {
            int gm = mb + wm + i * 16 + (lane >> 4) * 4 + r;
            if (gm >= M) continue;
            #pragma unroll
            for (int j = 0; j < 4; ++j) {
                int gn = nb + wn + j * 16 + (lane & 15);
                if (gn >= N) continue;
                size_t idx = (size_t)z * sC + (size_t)gm * ldc + gn;
                float v = acc[i][j][r];
                if (OUTF32) {
                    float prev = ACCUM ? Cf[idx] : 0.f;
                    Cf[idx] = prev + v;
                } else {
                    unsigned short h = f2bf(v);
                    Ch[idx] = h;
                    Cl[idx] = f2bf(v - bf2f(h));
                }
            }
        }
}

// ---------------------------------------------------------------------------
// softmax over 316 logits per (h,q); writes normalized first-16 back (fp32,
// for ka), s0, and the full padded bf16 hi/lo row aw[rid][0..319].
// ---------------------------------------------------------------------------
__global__ __launch_bounds__(256) void softmax_kernel(
    float* __restrict__ attn, float* __restrict__ s0,
    unsigned short* __restrict__ awh, unsigned short* __restrict__ awl)
{
    const int t = threadIdx.x;
    const int w = t >> 6, lane = t & 63;
    const int rid = blockIdx.x * 4 + w;     // h*2048 + q
    float* row = attn + (size_t)rid * NJ;
    float v[5];
    float m = -1e30f;
    #pragma unroll
    for (int i = 0; i < 5; ++i) {
        int j = lane + 64 * i;
        v[i] = (j < NJ) ? row[j] : -1e30f;
        m = fmaxf(m, v[i]);
    }
    #pragma unroll
    for (int d = 1; d < 64; d <<= 1) m = fmaxf(m, __shfl_xor(m, d));
    float s = 0.f, sfirst = 0.f;
    #pragma unroll
    for (int i = 0; i < 5; ++i) {
        int j = lane + 64 * i;
        float e = (j < NJ) ? expf(v[i] - m) : 0.f;
        v[i] = e;
        s += e;
        if (i == 0 && lane < 16) sfirst += e;
    }
    #pragma unroll
    for (int d = 1; d < 64; d <<= 1) s += __shfl_xor(s, d);
    #pragma unroll
    for (int d = 1; d < 64; d <<= 1) sfirst += __shfl_xor(sfirst, d);
    float inv = 1.f / s;
    #pragma unroll
    for (int i = 0; i < 5; ++i) {
        int j = lane + 64 * i;
        float val = (j < NJ) ? v[i] * inv : 0.f;
        if (j < 16) row[j] = val;           // ka reads these
        unsigned short h = f2bf(val);
        awh[(size_t)rid * 320 + j] = h;
        awl[(size_t)rid * 320 + j] = f2bf(val - bf2f(h));
    }
    if (lane == 0) s0[rid] = sfirst * inv;
}

// ---------------------------------------------------------------------------
// KA[h,q,e] = sum_{k<16} attn[h,q,k] * key_row(lin[q,h,k])[e] -> bf16 hi/lo
// ---------------------------------------------------------------------------
__global__ __launch_bounds__(256) void ka_kernel(
    const float* __restrict__ inflat, const float* __restrict__ attn,
    const int* __restrict__ lin, unsigned short* __restrict__ KAh,
    unsigned short* __restrict__ KAl)
{
    __shared__ float wls[16];
    __shared__ int lls[16];
    const int b = blockIdx.x;               // h*2048 + q
    const int h = b >> 11, q = b & 2047;
    const int t = threadIdx.x;
    if (t < 16) {
        wls[t] = attn[(size_t)b * NJ + t];
        lls[t] = lin[q * 128 + h * 16 + t];
    }
    __syncthreads();
    float acc = 0.f;
    #pragma unroll
    for (int k = 0; k < 16; ++k)
        acc += wls[k] * inflat[lls[k] * 256 + t];
    unsigned short hh = f2bf(acc);
    KAh[(size_t)b * 256 + t] = hh;
    KAl[(size_t)b * 256 + t] = f2bf(acc - bf2f(hh));
}

// ---------------------------------------------------------------------------
// final: per-channel head softmax + mix with bias terms.
// ---------------------------------------------------------------------------
__global__ __launch_bounds__(256) void final_kernel(
    const float* __restrict__ qf, const float* __restrict__ OH,
    const float* __restrict__ s0, const float* __restrict__ bv,
    const float* __restrict__ Wmix, float* __restrict__ out)
{
    const int q = blockIdx.x, c = threadIdx.x;
    float wj[9], m = -1e30f;
    #pragma unroll
    for (int j = 0; j < 9; ++j) { wj[j] = Wmix[c * 9 + j]; m = fmaxf(m, wj[j]); }
    float s = 0.f;
    #pragma unroll
    for (int j = 0; j < 9; ++j) { wj[j] = expf(wj[j] - m); s += wj[j]; }
    float inv = 1.f / s;
    float acc = qf[q * 256 + c] * wj[8] * inv;
    #pragma unroll
    for (int h = 0; h < 8; ++h) {
        float s0v = s0[h * 2048 + q];
        float oh = OH[((size_t)h * 2048 + q) * 256 + c]
                 + s0v * bv[(2 * h) * 256 + c]
                 + (1.f - s0v) * bv[(2 * h + 1) * 256 + c];
        acc += oh * wj[h] * inv;
    }
    out[q * 256 + c] = acc;
}

// ---------------------------------------------------------------------------
extern "C" void kernel_launch(void* const* d_in, const int* in_sizes, int n_in,
                              void* d_out, int out_size, void* d_ws, size_t ws_size,
                              hipStream_t stream) {
    const float* query = (const float*)d_in[0];
    const float* refp  = (const float*)d_in[1];
    const float* inflat= (const float*)d_in[2];
    const int*   iss   = (const int*)d_in[3];
    const float* ak    = (const float*)d_in[4];
    const int*   lsi   = (const int*)d_in[5];
    const float* Woff  = (const float*)d_in[6];
    const float* boff  = (const float*)d_in[7];
    const float* Wattn = (const float*)d_in[8];
    const float* Wv    = (const float*)d_in[9];
    const float* bv    = (const float*)d_in[10];
    const float* Wmix  = (const float*)d_in[11];
    float* out = (float*)d_out;

    typedef unsigned short us;
    char* ws = (char*)d_ws;
    int* lin    = (int*)ws;   ws += (size_t)262144 * 4;
    float* attn = (float*)ws; ws += (size_t)8 * 2048 * NJ * 4;
    float* s0   = (float*)ws; ws += (size_t)8 * 2048 * 4;
    us* qh  = (us*)ws; ws += (size_t)524288 * 2;
    us* ql  = (us*)ws; ws += (size_t)524288 * 2;
    us* akh = (us*)ws; ws += (size_t)320 * 256 * 2;
    us* akl = (us*)ws; ws += (size_t)320 * 256 * 2;
    us* Wah = (us*)ws; ws += (size_t)2621440 * 2;
    us* Wal = (us*)ws; ws += (size_t)2621440 * 2;
    us* Wvh = (us*)ws; ws += (size_t)1048576 * 2;
    us* Wvl = (us*)ws; ws += (size_t)1048576 * 2;
    us* akTh= (us*)ws; ws += (size_t)256 * 320 * 2;
    us* akTl= (us*)ws; ws += (size_t)256 * 320 * 2;
    us* Bhh = (us*)ws; ws += (size_t)8 * 320 * 256 * 2;
    us* Bhl = (us*)ws; ws += (size_t)8 * 320 * 256 * 2;
    us* awh = (us*)ws; ws += (size_t)8 * 2048 * 320 * 2;
    us* awl = (us*)ws; ws += (size_t)8 * 2048 * 320 * 2;
    us* KAh = (us*)ws; ws += (size_t)8 * 2048 * 256 * 2;
    us* KAl = (us*)ws; ws += (size_t)8 * 2048 * 256 * 2;
    us* AAh = (us*)ws; ws += (size_t)8 * 2048 * 256 * 2;
    us* AAl = (us*)ws; ws += (size_t)8 * 2048 * 256 * 2;
    float* OH = (float*)awh;  // alias: aw dead before OH is written (~96 MB total)

    cvt_kernel<<<256, 256, 0, stream>>>(query, qh, ql, 524288 / 4);
    cvt_kernel<<<75, 256, 0, stream>>>(ak, akh, akl, 76800 / 4);
    cvt_kernel<<<256, 256, 0, stream>>>(Wattn, Wah, Wal, 2621440 / 4);
    cvt_kernel<<<256, 256, 0, stream>>>(Wv, Wvh, Wvl, 1048576 / 4);
    cvt_akT_kernel<<<256, 256, 0, stream>>>(ak, akTh, akTl);
    lin_kernel<<<256, 256, 0, stream>>>(query, refp, iss, lsi, Woff, boff, lin);

    Seg sz = {nullptr, nullptr, nullptr, nullptr, 0, 0, 0, 0L, 0L};

    // Bh[z] = ak @ Wadd[z]^T  (M=300, N=256, K=256) -> bf16 hi/lo
    {
        Seg a = {akh, akl, Wah + 4 * 65536, Wal + 4 * 65536, 256, 256, 256,
                 0L, 4L * 65536};
        mfma_gemm<false, false, 1><<<dim3(2, 5, 8), 256, 0, stream>>>(
            a, sz, nullptr, Bhh, Bhl, 300, 256, 256, 320L * 256);
    }
    // attn_a logits = qf @ Bh^T  (M=2048, N=300, K=256) -> attn[...,16:]
    {
        Seg a = {qh, ql, Bhh, Bhl, 256, 256, 256, 0L, 320L * 256};
        mfma_gemm<false, true, 1><<<dim3(3, 32, 8), 256, 0, stream>>>(
            a, sz, attn + 16, nullptr, nullptr, 2048, 300, NJ, 2048L * NJ);
    }

    gattn_kernel<<<1024, 256, 0, stream>>>(query, inflat, Wattn, lin, attn);

    softmax_kernel<<<4096, 256, 0, stream>>>(attn, s0, awh, awl);

    ka_kernel<<<16384, 256, 0, stream>>>(inflat, attn, lin, KAh, KAl);

    // AA[z] = aw[z] @ akT^T  (M=2048, N=256, K=320) -> bf16 hi/lo
    {
        Seg a = {awh, awl, akTh, akTl, 320, 320, 320, 2048L * 320, 0L};
        mfma_gemm<false, false, 1><<<dim3(2, 32, 8), 256, 0, stream>>>(
            a, sz, nullptr, AAh, AAl, 2048, 256, 256, 2048L * 256);
    }
    // OH[z] = KA[z] @ Wv0[z]^T + AA[z] @ Wv1[z]^T  (fused two-segment)
    {
        Seg a = {KAh, KAl, Wvh, Wvl, 256, 256, 256, 2048L * 256, 2L * 65536};
        Seg b = {AAh, AAl, Wvh + 65536, Wvl + 65536, 256, 256, 256,
                 2048L * 256, 2L * 65536};
        mfma_gemm<false, true, 2><<<dim3(2, 32, 8), 256, 0, stream>>>(
            a, b, OH, nullptr, nullptr, 2048, 256, 256, 2048L * 256);
    }

    final_kernel<<<2048, 256, 0, stream>>>(query, OH, s0, bv, Wmix, out);
}

// Round 3
// 297.703 us; speedup vs baseline: 2.5689x; 1.1860x over previous
//
#include <hip/hip_runtime.h>
#include <stdint.h>

#define NJ 316  // L*P + Lx = 16 + 300

typedef __attribute__((ext_vector_type(8))) short short8;
typedef __attribute__((ext_vector_type(4))) float f32x4;
union U4S8 { uint4 u; short8 s; };

__device__ __forceinline__ unsigned short f2bf(float x) {
    unsigned int u = __float_as_uint(x);
    u += 0x7fff + ((u >> 16) & 1);
    return (unsigned short)(u >> 16);
}
__device__ __forceinline__ float bf2f(unsigned short h) {
    return __uint_as_float(((unsigned int)h) << 16);
}

// ---------------------------------------------------------------------------
// Elementwise fp32 -> (hi, lo) bf16 planes.
// ---------------------------------------------------------------------------
__global__ __launch_bounds__(256) void cvt_kernel(
    const float* __restrict__ src, unsigned short* __restrict__ dh,
    unsigned short* __restrict__ dl, int n4)
{
    for (int i = blockIdx.x * 256 + threadIdx.x; i < n4; i += gridDim.x * 256) {
        float4 v = ((const float4*)src)[i];
        unsigned short h[4], l[4];
        float x[4] = {v.x, v.y, v.z, v.w};
        #pragma unroll
        for (int j = 0; j < 4; ++j) {
            h[j] = f2bf(x[j]);
            l[j] = f2bf(x[j] - bf2f(h[j]));
        }
        ((uint2*)dh)[i] = make_uint2((unsigned)h[0] | ((unsigned)h[1] << 16),
                                     (unsigned)h[2] | ((unsigned)h[3] << 16));
        ((uint2*)dl)[i] = make_uint2((unsigned)l[0] | ((unsigned)l[1] << 16),
                                     (unsigned)l[2] | ((unsigned)l[3] << 16));
    }
}

// fp32 -> packed (lo16<<16 | hi16) per element (for gathered MFMA fragments)
__global__ __launch_bounds__(256) void cvt_pack_kernel(
    const float* __restrict__ src, unsigned int* __restrict__ dst, int n4)
{
    for (int i = blockIdx.x * 256 + threadIdx.x; i < n4; i += gridDim.x * 256) {
        float4 v = ((const float4*)src)[i];
        float x[4] = {v.x, v.y, v.z, v.w};
        unsigned int o[4];
        #pragma unroll
        for (int j = 0; j < 4; ++j) {
            unsigned short h = f2bf(x[j]);
            unsigned short l = f2bf(x[j] - bf2f(h));
            o[j] = (unsigned)h | ((unsigned)l << 16);
        }
        ((uint4*)dst)[i] = make_uint4(o[0], o[1], o[2], o[3]);
    }
}

// Wadd[h] = W_attn[4h+4] -> bf16 hi/lo planes [8][65536]
__global__ __launch_bounds__(256) void cvt_wadd_kernel(
    const float* __restrict__ Wattn, unsigned short* __restrict__ dh,
    unsigned short* __restrict__ dl)
{
    int i = blockIdx.x * 256 + threadIdx.x;      // 0 .. 524287
    int z = i >> 16, r = i & 65535;
    float v = Wattn[(size_t)(4 * z + 4) * 65536 + r];
    unsigned short h = f2bf(v);
    dh[i] = h;
    dl[i] = f2bf(v - bf2f(h));
}

// akT_pad[e][k]: k<16 -> 0, 16<=k<316 -> ak[k-16][e], k>=316 -> 0.  [256][320]
__global__ __launch_bounds__(256) void cvt_akT_kernel(
    const float* __restrict__ ak, unsigned short* __restrict__ dh,
    unsigned short* __restrict__ dl)
{
    const int e = blockIdx.x;
    for (int k = threadIdx.x; k < 320; k += 256) {
        float v = (k >= 16 && k < 316) ? ak[(k - 16) * 256 + e] : 0.f;
        unsigned short h = f2bf(v);
        dh[e * 320 + k] = h;
        dl[e * 320 + k] = f2bf(v - bf2f(h));
    }
}

// ---------------------------------------------------------------------------
// lin_kernel: fp64 offsets -> sampling indices (verified R1)
// ---------------------------------------------------------------------------
__global__ __launch_bounds__(256) void lin_kernel(
    const float* __restrict__ query, const float* __restrict__ refp,
    const int* __restrict__ iss, const int* __restrict__ lsi,
    const float* __restrict__ Woff, const float* __restrict__ boff,
    int* __restrict__ lin)
{
    __shared__ float qf8[8][256];
    __shared__ float wtile[256][33];
    __shared__ double offl[8][256];
    const int t = threadIdx.x;
    const int qbase = blockIdx.x * 8;
    #pragma unroll
    for (int i = 0; i < 8; ++i) qf8[i][t] = query[(qbase + i) * 256 + t];
    double acc[8];
    #pragma unroll
    for (int r = 0; r < 8; ++r) acc[r] = 0.0;
    for (int cb = 0; cb < 256; cb += 32) {
        __syncthreads();
        #pragma unroll
        for (int i = 0; i < 32; ++i) {
            int f = i * 256 + t;
            int o = f >> 5, jj = f & 31;
            wtile[o][jj] = Woff[o * 256 + cb + jj];
        }
        __syncthreads();
        #pragma unroll
        for (int jj = 0; jj < 32; ++jj) {
            double wv = (double)wtile[t][jj];
            #pragma unroll
            for (int r = 0; r < 8; ++r)
                acc[r] += (double)qf8[r][cb + jj] * wv;
        }
    }
    double bo = (double)boff[t];
    __syncthreads();
    #pragma unroll
    for (int r = 0; r < 8; ++r) offl[r][t] = acc[r] + bo;
    __syncthreads();
    #pragma unroll
    for (int rep = 0; rep < 4; ++rep) {
        int idx = rep * 256 + t;
        int r = idx >> 7;
        int s = idx & 127;
        int l = (s >> 2) & 3;
        int q = qbase + r;
        double offx = offl[r][2 * s];
        double offy = offl[r][2 * s + 1];
        int w0 = iss[l * 2 + 0];
        int w1 = iss[l * 2 + 1];
        double locx = (double)refp[q * 8 + l * 2 + 0] + offx / (double)w1;
        double locy = (double)refp[q * 8 + l * 2 + 1] + offy / (double)w0;
        locx = fmin(fmax(locx, 0.0), 0.999);
        locy = fmin(fmax(locy, 0.0), 0.999);
        int ix = (int)(locx * (double)w0);
        int iy = (int)(locy * (double)w1);
        lin[q * 128 + s] = ix + iy * w0 + lsi[l];
    }
}

// ---------------------------------------------------------------------------
// gattn_mfma: split-bf16 MFMA G-GEMM + fp32 shuffle epilogue.
// Block (h,l,p,qb): G[hi=0..63][e=0..255] = sum_j Q[q2(hi)][j] * K[j][e],
// q2 = qb+8p+32*hi, K[j] = inflat[linrow[j]].  Wave w owns e-slice [64w,64w+64).
// B-frags gathered directly from packed inflatP (no LDS staging).
// Then attn_s[p2,q2] = sum_e Wattn[h*4+l][hi+64p2][e] * G[hi][e]  (fp32 exact).
// ---------------------------------------------------------------------------
__global__ __launch_bounds__(256, 2) void gattn_mfma(
    const unsigned short* __restrict__ qh, const unsigned short* __restrict__ ql,
    const unsigned int* __restrict__ inflatP, const float* __restrict__ Wattn,
    const int* __restrict__ lin, float* __restrict__ attn)
{
    __shared__ int linrow[256];
    __shared__ float Glds[64][268];
    const int t = threadIdx.x;
    const int lane = t & 63, w = t >> 6;
    const int b = blockIdx.x;
    const int qb = b & 7, p = (b >> 3) & 3, l = (b >> 5) & 3, h = b >> 7;
    linrow[t] = lin[(256 * qb + t) * 128 + h * 16 + l * 4 + p];
    __syncthreads();

    const int l15 = lane & 15, g = lane >> 4;
    const int q2l = qb + 8 * p + 32 * l15;      // q2 for i=0; +512 per i
    const int ebase = 64 * w + l15;

    f32x4 acc[4][4];
    #pragma unroll
    for (int i = 0; i < 4; ++i)
        #pragma unroll
        for (int eg = 0; eg < 4; ++eg) acc[i][eg] = (f32x4){0.f, 0.f, 0.f, 0.f};

    for (int kb = 0; kb < 256; kb += 32) {
        // A fragments: one uint4 per (i, plane) straight from global (L1-hot)
        U4S8 ah[4], al[4];
        #pragma unroll
        for (int i = 0; i < 4; ++i) {
            size_t off = (size_t)(q2l + 512 * i) * 256 + kb + 8 * g;
            ah[i].u = *(const uint4*)(qh + off);
            al[i].u = *(const uint4*)(ql + off);
        }
        // B gather: lane (g, l15) covers k = 8g+m, e = ebase + 16*eg
        int rowoff[8];
        #pragma unroll
        for (int m = 0; m < 8; ++m) rowoff[m] = linrow[kb + 8 * g + m] * 256;
        unsigned int uv[4][8];
        #pragma unroll
        for (int eg = 0; eg < 4; ++eg)
            #pragma unroll
            for (int m = 0; m < 8; ++m)
                uv[eg][m] = inflatP[rowoff[m] + ebase + 16 * eg];

        #pragma unroll
        for (int eg = 0; eg < 4; ++eg) {
            U4S8 bh, bl;
            unsigned int hh[4], ll[4];
            #pragma unroll
            for (int d = 0; d < 4; ++d) {
                hh[d] = __builtin_amdgcn_perm(uv[eg][2 * d + 1], uv[eg][2 * d],
                                              0x05040100u);
                ll[d] = __builtin_amdgcn_perm(uv[eg][2 * d + 1], uv[eg][2 * d],
                                              0x07060302u);
            }
            bh.u = make_uint4(hh[0], hh[1], hh[2], hh[3]);
            bl.u = make_uint4(ll[0], ll[1], ll[2], ll[3]);
            #pragma unroll
            for (int i = 0; i < 4; ++i) {
                acc[i][eg] = __builtin_amdgcn_mfma_f32_16x16x32_bf16(
                    ah[i].s, bh.s, acc[i][eg], 0, 0, 0);
                acc[i][eg] = __builtin_amdgcn_mfma_f32_16x16x32_bf16(
                    ah[i].s, bl.s, acc[i][eg], 0, 0, 0);
                acc[i][eg] = __builtin_amdgcn_mfma_f32_16x16x32_bf16(
                    al[i].s, bh.s, acc[i][eg], 0, 0, 0);
            }
        }
    }

    // dump G (C-layout: row = 16i+4g+r, col = 64w+16eg+l15) to LDS
    #pragma unroll
    for (int i = 0; i < 4; ++i)
        #pragma unroll
        for (int eg = 0; eg < 4; ++eg)
            #pragma unroll
            for (int r = 0; r < 4; ++r)
                Glds[16 * i + 4 * g + r][64 * w + 16 * eg + l15] = acc[i][eg][r];
    __syncthreads();

    // fp32 epilogue (R1-verified): contract G rows with Ws rows, shuffle over tx
    const int tx = t & 15, ty = t >> 4;
    const float* Wsbase = Wattn + (size_t)(h * 4 + l) * 65536;
    float gv[4][16];
    #pragma unroll
    for (int r = 0; r < 4; ++r)
        #pragma unroll
        for (int i2 = 0; i2 < 4; ++i2) {
            float4 gd = *(const float4*)&Glds[ty * 4 + r][tx * 4 + 64 * i2];
            gv[r][i2 * 4 + 0] = gd.x;
            gv[r][i2 * 4 + 1] = gd.y;
            gv[r][i2 * 4 + 2] = gd.z;
            gv[r][i2 * 4 + 3] = gd.w;
        }
    #pragma unroll
    for (int r = 0; r < 4; ++r) {
        int hi = ty * 4 + r;
        int q2 = qb + 8 * p + 32 * hi;
        #pragma unroll
        for (int p2 = 0; p2 < 4; ++p2) {
            const float* wr = Wsbase + (size_t)(hi + 64 * p2) * 256;
            float partial = 0.f;
            #pragma unroll
            for (int i2 = 0; i2 < 4; ++i2) {
                float4 wv = *(const float4*)&wr[tx * 4 + 64 * i2];
                partial += wv.x * gv[r][i2 * 4 + 0] + wv.y * gv[r][i2 * 4 + 1]
                         + wv.z * gv[r][i2 * 4 + 2] + wv.w * gv[r][i2 * 4 + 3];
            }
            partial += __shfl_xor(partial, 1);
            partial += __shfl_xor(partial, 2);
            partial += __shfl_xor(partial, 4);
            partial += __shfl_xor(partial, 8);
            if (tx == 0)
                attn[((size_t)h * 2048 + q2) * NJ + (l * 4 + p2)] = partial;
        }
    }
}

// ---------------------------------------------------------------------------
// Split-bf16 MFMA GEMM (verified R2). BM=64 BN=128 BK=32, 4 waves.
// ---------------------------------------------------------------------------
struct Seg {
    const unsigned short *Ah, *Al, *Bh, *Bl;
    int K, lda, ldb;
    long sA, sB;
};

template<bool ACCUM, bool OUTF32, int NSEG>
__global__ __launch_bounds__(256) void mfma_gemm(
    Seg s0, Seg s1,
    float* __restrict__ Cf, unsigned short* __restrict__ Ch,
    unsigned short* __restrict__ Cl,
    int M, int N, int ldc, long sC)
{
    __shared__ unsigned short As[2][64 * 40];
    __shared__ unsigned short Bs[2][128 * 40];
    const int t = threadIdx.x;
    const int lane = t & 63;
    const int wave = t >> 6;
    const int wm = (wave & 1) * 32, wn = (wave >> 1) * 64;
    const int nb = blockIdx.x * 128, mb = blockIdx.y * 64;
    const int z = blockIdx.z;

    f32x4 acc[2][4];
    #pragma unroll
    for (int i = 0; i < 2; ++i)
        #pragma unroll
        for (int j = 0; j < 4; ++j) acc[i][j] = (f32x4){0.f, 0.f, 0.f, 0.f};

    const int arow = t >> 2, akoff = (t & 3) * 8;
    const int frow = lane & 15, fk = (lane >> 4) * 8;

    #pragma unroll
    for (int seg = 0; seg < NSEG; ++seg) {
        const Seg S = seg ? s1 : s0;
        const unsigned short* Azh = S.Ah + (size_t)z * S.sA;
        const unsigned short* Azl = S.Al + (size_t)z * S.sA;
        const unsigned short* Bzh = S.Bh + (size_t)z * S.sB;
        const unsigned short* Bzl = S.Bl + (size_t)z * S.sB;
        for (int kb = 0; kb < S.K; kb += 32) {
            __syncthreads();
            {
                int gm = mb + arow;
                uint4 vh = {0, 0, 0, 0}, vl = {0, 0, 0, 0};
                if (gm < M) {
                    size_t o = (size_t)gm * S.lda + kb + akoff;
                    vh = *(const uint4*)(Azh + o);
                    vl = *(const uint4*)(Azl + o);
                }
                *(uint4*)&As[0][arow * 40 + akoff] = vh;
                *(uint4*)&As[1][arow * 40 + akoff] = vl;
                #pragma unroll
                for (int i = 0; i < 2; ++i) {
                    int f = i * 256 + t;
                    int brow = f >> 2, bkoff = (f & 3) * 8;
                    int gn = nb + brow;
                    uint4 wh = {0, 0, 0, 0}, wl = {0, 0, 0, 0};
                    if (gn < N) {
                        size_t o = (size_t)gn * S.ldb + kb + bkoff;
                        wh = *(const uint4*)(Bzh + o);
                        wl = *(const uint4*)(Bzl + o);
                    }
                    *(uint4*)&Bs[0][brow * 40 + bkoff] = wh;
                    *(uint4*)&Bs[1][brow * 40 + bkoff] = wl;
                }
            }
            __syncthreads();
            short8 a[2][2], b[4][2];
            #pragma unroll
            for (int i = 0; i < 2; ++i) {
                int r = wm + i * 16 + frow;
                a[i][0] = *(const short8*)&As[0][r * 40 + fk];
                a[i][1] = *(const short8*)&As[1][r * 40 + fk];
            }
            #pragma unroll
            for (int j = 0; j < 4; ++j) {
                int r = wn + j * 16 + frow;
                b[j][0] = *(const short8*)&Bs[0][r * 40 + fk];
                b[j][1] = *(const short8*)&Bs[1][r * 40 + fk];
            }
            #pragma unroll
            for (int i = 0; i < 2; ++i)
                #pragma unroll
                for (int j = 0; j < 4; ++j) {
                    acc[i][j] = __builtin_amdgcn_mfma_f32_16x16x32_bf16(
                        a[i][0], b[j][0], acc[i][j], 0, 0, 0);
                    acc[i][j] = __builtin_amdgcn_mfma_f32_16x16x32_bf16(
                        a[i][0], b[j][1], acc[i][j], 0, 0, 0);
                    acc[i][j] = __builtin_amdgcn_mfma_f32_16x16x32_bf16(
                        a[i][1], b[j][0], acc[i][j], 0, 0, 0);
                }
        }
    }
    #pragma unroll
    for (int i = 0; i < 2; ++i)
        #pragma unroll
        for (int r = 0; r < 4; ++r) {
            int gm = mb + wm + i * 16 + (lane >> 4) * 4 + r;
            if (gm >= M) continue;
            #pragma unroll
            for (int j = 0; j < 4; ++j) {
                int gn = nb + wn + j * 16 + (lane & 15);
                if (gn >= N) continue;
                size_t idx = (size_t)z * sC + (size_t)gm * ldc + gn;
                float v = acc[i][j][r];
                if (OUTF32) {
                    float prev = ACCUM ? Cf[idx] : 0.f;
                    Cf[idx] = prev + v;
                } else {
                    unsigned short h = f2bf(v);
                    Ch[idx] = h;
                    Cl[idx] = f2bf(v - bf2f(h));
                }
            }
        }
}

// ---------------------------------------------------------------------------
// softmax over 316 logits per (h,q); emits s0 and padded bf16 hi/lo row.
// ---------------------------------------------------------------------------
__global__ __launch_bounds__(256) void softmax_kernel(
    float* __restrict__ attn, float* __restrict__ s0,
    unsigned short* __restrict__ awh, unsigned short* __restrict__ awl)
{
    const int t = threadIdx.x;
    const int w = t >> 6, lane = t & 63;
    const int rid = blockIdx.x * 4 + w;     // h*2048 + q
    float* row = attn + (size_t)rid * NJ;
    float v[5];
    float m = -1e30f;
    #pragma unroll
    for (int i = 0; i < 5; ++i) {
        int j = lane + 64 * i;
        v[i] = (j < NJ) ? row[j] : -1e30f;
        m = fmaxf(m, v[i]);
    }
    #pragma unroll
    for (int d = 1; d < 64; d <<= 1) m = fmaxf(m, __shfl_xor(m, d));
    float s = 0.f, sfirst = 0.f;
    #pragma unroll
    for (int i = 0; i < 5; ++i) {
        int j = lane + 64 * i;
        float e = (j < NJ) ? expf(v[i] - m) : 0.f;
        v[i] = e;
        s += e;
        if (i == 0 && lane < 16) sfirst += e;
    }
    #pragma unroll
    for (int d = 1; d < 64; d <<= 1) s += __shfl_xor(s, d);
    #pragma unroll
    for (int d = 1; d < 64; d <<= 1) sfirst += __shfl_xor(sfirst, d);
    float inv = 1.f / s;
    #pragma unroll
    for (int i = 0; i < 5; ++i) {
        int j = lane + 64 * i;
        float val = (j < NJ) ? v[i] * inv : 0.f;
        if (j < 16) row[j] = val;
        unsigned short h = f2bf(val);
        awh[(size_t)rid * 320 + j] = h;
        awl[(size_t)rid * 320 + j] = f2bf(val - bf2f(h));
    }
    if (lane == 0) s0[rid] = sfirst * inv;
}

// ---------------------------------------------------------------------------
// KA[h,q,e] = sum_{k<16} attn[h,q,k] * key_row(lin[q,h,k])[e] -> bf16 hi/lo
// ---------------------------------------------------------------------------
__global__ __launch_bounds__(256) void ka_kernel(
    const float* __restrict__ inflat, const float* __restrict__ attn,
    const int* __restrict__ lin, unsigned short* __restrict__ KAh,
    unsigned short* __restrict__ KAl)
{
    __shared__ float wls[16];
    __shared__ int lls[16];
    const int b = blockIdx.x;               // h*2048 + q
    const int h = b >> 11, q = b & 2047;
    const int t = threadIdx.x;
    if (t < 16) {
        wls[t] = attn[(size_t)b * NJ + t];
        lls[t] = lin[q * 128 + h * 16 + t];
    }
    __syncthreads();
    float acc = 0.f;
    #pragma unroll
    for (int k = 0; k < 16; ++k)
        acc += wls[k] * inflat[lls[k] * 256 + t];
    unsigned short hh = f2bf(acc);
    KAh[(size_t)b * 256 + t] = hh;
    KAl[(size_t)b * 256 + t] = f2bf(acc - bf2f(hh));
}

// ---------------------------------------------------------------------------
__global__ __launch_bounds__(256) void final_kernel(
    const float* __restrict__ qf, const float* __restrict__ OH,
    const float* __restrict__ s0, const float* __restrict__ bv,
    const float* __restrict__ Wmix, float* __restrict__ out)
{
    const int q = blockIdx.x, c = threadIdx.x;
    float wj[9], m = -1e30f;
    #pragma unroll
    for (int j = 0; j < 9; ++j) { wj[j] = Wmix[c * 9 + j]; m = fmaxf(m, wj[j]); }
    float s = 0.f;
    #pragma unroll
    for (int j = 0; j < 9; ++j) { wj[j] = expf(wj[j] - m); s += wj[j]; }
    float inv = 1.f / s;
    float acc = qf[q * 256 + c] * wj[8] * inv;
    #pragma unroll
    for (int h = 0; h < 8; ++h) {
        float s0v = s0[h * 2048 + q];
        float oh = OH[((size_t)h * 2048 + q) * 256 + c]
                 + s0v * bv[(2 * h) * 256 + c]
                 + (1.f - s0v) * bv[(2 * h + 1) * 256 + c];
        acc += oh * wj[h] * inv;
    }
    out[q * 256 + c] = acc;
}

// ---------------------------------------------------------------------------
extern "C" void kernel_launch(void* const* d_in, const int* in_sizes, int n_in,
                              void* d_out, int out_size, void* d_ws, size_t ws_size,
                              hipStream_t stream) {
    const float* query = (const float*)d_in[0];
    const float* refp  = (const float*)d_in[1];
    const float* inflat= (const float*)d_in[2];
    const int*   iss   = (const int*)d_in[3];
    const float* ak    = (const float*)d_in[4];
    const int*   lsi   = (const int*)d_in[5];
    const float* Woff  = (const float*)d_in[6];
    const float* boff  = (const float*)d_in[7];
    const float* Wattn = (const float*)d_in[8];
    const float* Wv    = (const float*)d_in[9];
    const float* bv    = (const float*)d_in[10];
    const float* Wmix  = (const float*)d_in[11];
    float* out = (float*)d_out;

    typedef unsigned short us;
    char* ws = (char*)d_ws;
    int* lin    = (int*)ws;   ws += (size_t)262144 * 4;
    float* attn = (float*)ws; ws += (size_t)8 * 2048 * NJ * 4;
    float* s0   = (float*)ws; ws += (size_t)8 * 2048 * 4;
    unsigned int* inflatP = (unsigned int*)ws; ws += (size_t)1392640 * 4;
    us* qh  = (us*)ws; ws += (size_t)524288 * 2;
    us* ql  = (us*)ws; ws += (size_t)524288 * 2;
    us* akh = (us*)ws; ws += (size_t)320 * 256 * 2;
    us* akl = (us*)ws; ws += (size_t)320 * 256 * 2;
    us* Waddh = (us*)ws; ws += (size_t)524288 * 2;
    us* Waddl = (us*)ws; ws += (size_t)524288 * 2;
    us* Wvh = (us*)ws; ws += (size_t)1048576 * 2;
    us* Wvl = (us*)ws; ws += (size_t)1048576 * 2;
    us* akTh= (us*)ws; ws += (size_t)256 * 320 * 2;
    us* akTl= (us*)ws; ws += (size_t)256 * 320 * 2;
    us* Bhh = (us*)ws; ws += (size_t)8 * 320 * 256 * 2;
    us* Bhl = (us*)ws; ws += (size_t)8 * 320 * 256 * 2;
    us* awh = (us*)ws; ws += (size_t)8 * 2048 * 320 * 2;
    us* awl = (us*)ws; ws += (size_t)8 * 2048 * 320 * 2;
    us* KAh = (us*)ws; ws += (size_t)8 * 2048 * 256 * 2;
    us* KAl = (us*)ws; ws += (size_t)8 * 2048 * 256 * 2;
    us* AAh = (us*)ws; ws += (size_t)8 * 2048 * 256 * 2;
    us* AAl = (us*)ws; ws += (size_t)8 * 2048 * 256 * 2;
    float* OH = (float*)awh;  // alias: aw dead before OH is written

    cvt_kernel<<<256, 256, 0, stream>>>(query, qh, ql, 524288 / 4);
    cvt_kernel<<<75, 256, 0, stream>>>(ak, akh, akl, 76800 / 4);
    cvt_pack_kernel<<<256, 256, 0, stream>>>(inflat, inflatP, 1392640 / 4);
    cvt_wadd_kernel<<<2048, 256, 0, stream>>>(Wattn, Waddh, Waddl);
    cvt_kernel<<<256, 256, 0, stream>>>(Wv, Wvh, Wvl, 1048576 / 4);
    cvt_akT_kernel<<<256, 256, 0, stream>>>(ak, akTh, akTl);
    lin_kernel<<<256, 256, 0, stream>>>(query, refp, iss, lsi, Woff, boff, lin);

    Seg sz = {nullptr, nullptr, nullptr, nullptr, 0, 0, 0, 0L, 0L};

    // Bh[z] = ak @ Wadd[z]^T  (M=300, N=256, K=256) -> bf16 hi/lo
    {
        Seg a = {akh, akl, Waddh, Waddl, 256, 256, 256, 0L, 65536L};
        mfma_gemm<false, false, 1><<<dim3(2, 5, 8), 256, 0, stream>>>(
            a, sz, nullptr, Bhh, Bhl, 300, 256, 256, 320L * 256);
    }
    // attn_a logits = qf @ Bh^T  (M=2048, N=300, K=256) -> attn[...,16:]
    {
        Seg a = {qh, ql, Bhh, Bhl, 256, 256, 256, 0L, 320L * 256};
        mfma_gemm<false, true, 1><<<dim3(3, 32, 8), 256, 0, stream>>>(
            a, sz, attn + 16, nullptr, nullptr, 2048, 300, NJ, 2048L * NJ);
    }

    gattn_mfma<<<1024, 256, 0, stream>>>(qh, ql, inflatP, Wattn, lin, attn);

    softmax_kernel<<<4096, 256, 0, stream>>>(attn, s0, awh, awl);

    ka_kernel<<<16384, 256, 0, stream>>>(inflat, attn, lin, KAh, KAl);

    // AA[z] = aw[z] @ akT^T  (M=2048, N=256, K=320) -> bf16 hi/lo
    {
        Seg a = {awh, awl, akTh, akTl, 320, 320, 320, 2048L * 320, 0L};
        mfma_gemm<false, false, 1><<<dim3(2, 32, 8), 256, 0, stream>>>(
            a, sz, nullptr, AAh, AAl, 2048, 256, 256, 2048L * 256);
    }
    // OH[z] = KA[z] @ Wv0[z]^T + AA[z] @ Wv1[z]^T  (fused two-segment)
    {
        Seg a = {KAh, KAl, Wvh, Wvl, 256, 256, 256, 2048L * 256, 2L * 65536};
        Seg b = {AAh, AAl, Wvh + 65536, Wvl + 65536, 256, 256, 256,
                 2048L * 256, 2L * 65536};
        mfma_gemm<false, true, 2><<<dim3(2, 32, 8), 256, 0, stream>>>(
            a, b, OH, nullptr, nullptr, 2048, 256, 256, 2048L * 256);
    }

    final_kernel<<<2048, 256, 0, stream>>>(query, OH, s0, bv, Wmix, out);
}